// Round 7
// baseline (677.605 us; speedup 1.0000x reference)
//
#include <hip/hip_runtime.h>

// Linear SSM group scan, R7: pk_fma issue-width pass on kPre/kA/kC.
// G=2, B=128, L=2048, SD=64, ID=16, OD=16. All fp32, exact decomposition.
//
// Pipeline:
//  kPre  : D[l,g,b,:] = SW@wn + B@u  (LDS-tiled GEMM) -> states region of out.
//          Inner loop packed: v_pk_fma_f32 with op_sel broadcast of the
//          w-operand (8 pk vs 16 scalar fma per k).
//  kA    : zero-init chunk recurrence, F-only; F rows via v_pk_fma_f32 with
//          the wave-uniform row pair in SGPRs (32 pk vs 64 fma per row).
//          R4's SGPR-pressure regression doesn't apply: row stream is now
//          64 dwords (F only), not 144 ([F|SW|B]).
//  kBscan2: 3-phase block-local init4 scan (unchanged from R6).
//  kC    : true chunk recurrence + fused obs; F rows and H/SV rows via
//          SGPR-pair pk_fma.
#define G_ 2
#define B_ 128
#define L_ 2048
#define SD 64
#define ID 16
#define OD 16
#define NC4 512
#define ROWP 68  // padded LDS row stride (dwords) for 64x64 matrices
#define OBS_BASE ((size_t)(G_) * B_ * L_ * SD)

typedef float v2 __attribute__((ext_vector_type(2)));

static __device__ __forceinline__ size_t slotof(int g, int b, int l) {
  return (((size_t)g * B_ + b) * L_ + l) * (size_t)SD;
}
// obs-region scratch slot: 64 floats per (g,b,c4) == obs[g,b,l0..l0+3,:]
static __device__ __forceinline__ size_t oslot(int g, int b, int c4) {
  return OBS_BASE + (((size_t)g * B_ + b) * L_ + (size_t)c4 * 4) * OD;
}
static __device__ __forceinline__ float rl(float v, int lane) {
  return __builtin_bit_cast(float, __builtin_amdgcn_readlane(__builtin_bit_cast(int, v), lane));
}
// acc += m * z, packed fp32; m wave-uniform (SGPR pair), z per-lane (VGPRs).
static __device__ __forceinline__ void pkfma_s(v2& acc, v2 m, v2 z) {
  asm("v_pk_fma_f32 %0, %1, %2, %0" : "+v"(acc) : "s"(m), "v"(z));
}
// acc += a * broadcast(w.lo)  /  acc += a * broadcast(w.hi)   (all VGPR)
static __device__ __forceinline__ void pkfma_blo(v2& acc, v2 a, v2 w) {
  asm("v_pk_fma_f32 %0, %1, %2, %0 op_sel:[0,0,0] op_sel_hi:[1,0,1]"
      : "+v"(acc) : "v"(a), "v"(w));
}
static __device__ __forceinline__ void pkfma_bhi(v2& acc, v2 a, v2 w) {
  asm("v_pk_fma_f32 %0, %1, %2, %0 op_sel:[0,1,0] op_sel_hi:[1,1,1]"
      : "+v"(acc) : "v"(a), "v"(w));
}
// LDS-only barrier: order ds ops without draining vmcnt.
static __device__ __forceinline__ void lds_barrier() {
  asm volatile("s_waitcnt lgkmcnt(0)\n\ts_barrier" ::: "memory");
}

// s' = A*s + add, lane = component. A rows (row=lane) in fr2 (32 v2 regs).
static __device__ __forceinline__ float a_step(const v2 (&fr2)[32], float s, float add) {
  v2 a0 = {add, 0.f}, a1 = {0.f, 0.f}, a2 = {0.f, 0.f}, a3 = {0.f, 0.f};
#pragma unroll
  for (int k2 = 0; k2 < 32; ++k2) {
    v2 m;
    m.x = rl(s, 2 * k2);
    m.y = rl(s, 2 * k2 + 1);
    if ((k2 & 3) == 0)      pkfma_s(a0, m, fr2[k2]);
    else if ((k2 & 3) == 1) pkfma_s(a1, m, fr2[k2]);
    else if ((k2 & 3) == 2) pkfma_s(a2, m, fr2[k2]);
    else                    pkfma_s(a3, m, fr2[k2]);
  }
  v2 aa = (a0 + a1) + (a2 + a3);
  return aa.x + aa.y;
}

// C = A*A (64x64, ROWP-padded LDS), 256 threads. Caller syncs before/after.
static __device__ void lds_sq_p(const float* A, float* C, int tid) {
  const int r = tid & 63, q = tid >> 6;
  const float4* Ar = (const float4*)(A + r * ROWP);
  float acc[16];
#pragma unroll
  for (int c = 0; c < 16; ++c) acc[c] = 0.f;
#pragma unroll 1
  for (int k4 = 0; k4 < 16; ++k4) {
    float4 af = Ar[k4];
#pragma unroll
    for (int kk = 0; kk < 4; ++kk) {
      float a = (kk == 0) ? af.x : (kk == 1) ? af.y : (kk == 2) ? af.z : af.w;
      const float4* Bk = (const float4*)(A + (k4 * 4 + kk) * ROWP + q * 16);
#pragma unroll
      for (int c = 0; c < 4; ++c) {
        float4 bv = Bk[c];
        acc[4 * c + 0] = fmaf(a, bv.x, acc[4 * c + 0]);
        acc[4 * c + 1] = fmaf(a, bv.y, acc[4 * c + 1]);
        acc[4 * c + 2] = fmaf(a, bv.z, acc[4 * c + 2]);
        acc[4 * c + 3] = fmaf(a, bv.w, acc[4 * c + 3]);
      }
    }
  }
  float4* Cr = (float4*)(C + r * ROWP + q * 16);
#pragma unroll
  for (int c = 0; c < 4; ++c)
    Cr[c] = make_float4(acc[4 * c], acc[4 * c + 1], acc[4 * c + 2], acc[4 * c + 3]);
}

// ---------------------------------------------------------------------------
// kPre: D = SW@wn + B@u for one (g, l, b-half) per block -> state slots.
// ---------------------------------------------------------------------------
__global__ __launch_bounds__(256) void kPre(
    const float* __restrict__ wn, const float* __restrict__ inp,
    const float* __restrict__ SW, const float* __restrict__ Bm,
    float* __restrict__ out) {
  __shared__ __align__(16) float Mt[80 * 64];  // k<64: SW^T, k>=64: B^T
  __shared__ __align__(16) float Nt[80 * 64];  // k<64: wn^T, k>=64: u^T
  const int tid = threadIdx.x;
  const int bid = (int)blockIdx.x;
  const int g = bid >> 12;
  const int rem = bid & 4095;
  const int l = rem >> 1;
  const int b0 = (rem & 1) * 64;
  {
    const int row = tid >> 2;
    const int k0 = (tid & 3) * 16;
    const float4* sp = (const float4*)(SW + (g * SD + row) * SD + k0);
#pragma unroll
    for (int q = 0; q < 4; ++q) {
      float4 v = sp[q];
      Mt[(k0 + 4 * q + 0) * 64 + row] = v.x;
      Mt[(k0 + 4 * q + 1) * 64 + row] = v.y;
      Mt[(k0 + 4 * q + 2) * 64 + row] = v.z;
      Mt[(k0 + 4 * q + 3) * 64 + row] = v.w;
    }
    const int k2 = (tid & 3) * 4;
    float4 bv = *(const float4*)(Bm + (g * SD + row) * ID + k2);
    Mt[(64 + k2 + 0) * 64 + row] = bv.x;
    Mt[(64 + k2 + 1) * 64 + row] = bv.y;
    Mt[(64 + k2 + 2) * 64 + row] = bv.z;
    Mt[(64 + k2 + 3) * 64 + row] = bv.w;
  }
  {
    const int item = tid & 63;
    const int kq = tid >> 6;
    const float4* wp =
        (const float4*)(wn + (((size_t)l * G_ + g) * B_ + b0 + item) * SD + kq * 16);
#pragma unroll
    for (int q = 0; q < 4; ++q) {
      float4 v = wp[q];
      const int k = kq * 16 + 4 * q;
      Nt[(k + 0) * 64 + item] = v.x;
      Nt[(k + 1) * 64 + item] = v.y;
      Nt[(k + 2) * 64 + item] = v.z;
      Nt[(k + 3) * 64 + item] = v.w;
    }
    const int item2 = tid >> 2;
    const int k2 = (tid & 3) * 4;
    float4 uv = *(const float4*)(inp + (((size_t)g * B_ + b0 + item2) * L_ + l) * ID + k2);
    Nt[(64 + k2 + 0) * 64 + item2] = uv.x;
    Nt[(64 + k2 + 1) * 64 + item2] = uv.y;
    Nt[(64 + k2 + 2) * 64 + item2] = uv.z;
    Nt[(64 + k2 + 3) * 64 + item2] = uv.w;
  }
  __syncthreads();
  const int i0 = (tid & 15) * 4;
  const int r0 = (tid >> 4) * 4;
  // acc2[r2][i]: .x = row 2*r2, .y = row 2*r2+1, output item i0+i
  v2 acc2[2][4];
#pragma unroll
  for (int r = 0; r < 2; ++r)
#pragma unroll
    for (int i = 0; i < 4; ++i) acc2[r][i] = (v2){0.f, 0.f};
#pragma unroll 4
  for (int k = 0; k < 80; ++k) {
    const v2* ap = (const v2*)(Mt + k * 64 + r0);  // rows r0..r0+3 (2 pairs)
    const v2* wp = (const v2*)(Nt + k * 64 + i0);  // items i0..i0+3 (2 pairs)
    v2 a20 = ap[0], a21 = ap[1];
    v2 w20 = wp[0], w21 = wp[1];
#pragma unroll
    for (int r = 0; r < 2; ++r) {
      v2 ar = (r == 0) ? a20 : a21;
      pkfma_blo(acc2[r][0], ar, w20);
      pkfma_bhi(acc2[r][1], ar, w20);
      pkfma_blo(acc2[r][2], ar, w21);
      pkfma_bhi(acc2[r][3], ar, w21);
    }
  }
#pragma unroll
  for (int i = 0; i < 4; ++i) {
    float4 v = make_float4(acc2[0][i].x, acc2[0][i].y, acc2[1][i].x, acc2[1][i].y);
    *(float4*)(out + slotof(g, b0 + i0 + i, l) + r0) = v;
  }
}

// ---------------------------------------------------------------------------
// kA: zero-init chunk recurrence, F-only. z(l0) = D[l0]; 3 F-steps; writes
// zend4(c4) to obs scratch. Grid 2048: (g, half, c4).
// ---------------------------------------------------------------------------
__global__ __launch_bounds__(256, 2) void kA(const float* __restrict__ Fm,
                                             float* __restrict__ out) {
  __shared__ __align__(16) float zb[SD * 64];  // [comp][item]
  const int tid = threadIdx.x;
  const int bid = (int)blockIdx.x;
  const int c4 = bid & (NC4 - 1);
  const int half = (bid >> 9) & 1;
  const int g = bid >> 10;
  const int l0 = c4 * 4;
  const int lane = tid & 63;
  const int ww = __builtin_amdgcn_readfirstlane(tid >> 6);
  const int b = half * 64 + lane;
  const int row0 = ww * 16;
  const float* __restrict__ Fg = Fm + g * SD * SD;

  v2 z2[32];
  {
    const float4* ip = (const float4*)(out + slotof(g, b, l0));  // D[l0]
#pragma unroll
    for (int q = 0; q < 16; ++q) {
      float4 f = ip[q];
      z2[2 * q] = (v2){f.x, f.y};
      z2[2 * q + 1] = (v2){f.z, f.w};
    }
  }
  float4 d4[4];
  {
    const float4* dp = (const float4*)(out + slotof(g, b, l0 + 1) + row0);
#pragma unroll
    for (int q = 0; q < 4; ++q) d4[q] = dp[q];
  }

#pragma unroll 1
  for (int j = 1; j < 4; ++j) {
    if (j != 1) lds_barrier();  // prev regather drained
#pragma unroll
    for (int c = 0; c < 16; ++c) {
      const int row = row0 + c;
      const v2* fr = (const v2*)(Fg + row * SD);  // uniform -> SGPR pairs
      v2 a0 = {0.f, 0.f}, a1 = {0.f, 0.f}, a2 = {0.f, 0.f}, a3 = {0.f, 0.f};
#pragma unroll
      for (int q = 0; q < 8; ++q) {
        pkfma_s(a0, fr[4 * q + 0], z2[4 * q + 0]);
        pkfma_s(a1, fr[4 * q + 1], z2[4 * q + 1]);
        pkfma_s(a2, fr[4 * q + 2], z2[4 * q + 2]);
        pkfma_s(a3, fr[4 * q + 3], z2[4 * q + 3]);
      }
      v2 aa = (a0 + a1) + (a2 + a3);
      float dv = ((c & 3) == 0) ? d4[c >> 2].x
               : ((c & 3) == 1) ? d4[c >> 2].y
               : ((c & 3) == 2) ? d4[c >> 2].z : d4[c >> 2].w;
      zb[row * 64 + lane] = aa.x + aa.y + dv;
    }
    float4 d4n[4];
    if (j != 3) {  // prefetch D[l0+j+1]; in flight across barrier + regather
      const float4* dp = (const float4*)(out + slotof(g, b, l0 + j + 1) + row0);
#pragma unroll
      for (int q = 0; q < 4; ++q) d4n[q] = dp[q];
    }
    lds_barrier();  // zb complete
    if (j != 3) {
#pragma unroll
      for (int k = 0; k < 32; ++k)
        z2[k] = (v2){zb[(2 * k) * 64 + lane], zb[(2 * k + 1) * 64 + lane]};
#pragma unroll
      for (int q = 0; q < 4; ++q) d4[q] = d4n[q];
    }
  }
  // cooperative zend4 store -> obs scratch slot(c4)
  {
    const int item = tid & 63;
    const int kg = tid >> 6;
    float* dst = out + oslot(g, half * 64 + item, c4);
#pragma unroll
    for (int r = 0; r < 4; ++r) {
      float4 v;
      v.x = zb[(kg * 16 + 4 * r + 0) * 64 + item];
      v.y = zb[(kg * 16 + 4 * r + 1) * 64 + item];
      v.z = zb[(kg * 16 + 4 * r + 2) * 64 + item];
      v.w = zb[(kg * 16 + 4 * r + 3) * 64 + item];
      ((float4*)dst)[kg * 4 + r] = v;
    }
  }
}

// ---------------------------------------------------------------------------
// kBscan2: 3-phase init4 scan. Block = (g,b), 1024 threads, 16 waves.
// ---------------------------------------------------------------------------
__global__ __launch_bounds__(1024, 4) void kBscan2(const float* __restrict__ Fm,
                                                   const float* __restrict__ s0,
                                                   float* __restrict__ out) {
  __shared__ __align__(16) float bufA[SD * ROWP];
  __shared__ __align__(16) float bufB[SD * ROWP];
  __shared__ float carr[16][64];
  __shared__ float gbuf[16][64];
  const int tid = threadIdx.x;
  const int bid = (int)blockIdx.x;
  const int g = bid >> 7;
  const int b = bid & 127;
  const int lane = tid & 63;
  const int w = __builtin_amdgcn_readfirstlane(tid >> 6);

  {
    const float* Fg = Fm + g * SD * SD;
    for (int i = tid; i < SD * SD; i += 1024)
      bufA[(i >> 6) * ROWP + (i & 63)] = Fg[i];
  }
  __syncthreads();
  if (tid < 256) lds_sq_p(bufA, bufB, tid);
  __syncthreads();
  if (tid < 256) lds_sq_p(bufB, bufA, tid);
  __syncthreads();
  v2 fr2[32];  // row `lane` of F^4
  {
    const v2* rp = (const v2*)(bufA + lane * ROWP);
#pragma unroll
    for (int k = 0; k < 32; ++k) fr2[k] = rp[k];
  }
  __syncthreads();
  if (tid < 256) lds_sq_p(bufA, bufB, tid);
  __syncthreads();
  if (tid < 256) lds_sq_p(bufB, bufA, tid);
  __syncthreads();
  if (tid < 256) lds_sq_p(bufA, bufB, tid);
  __syncthreads();
  if (tid < 256) lds_sq_p(bufB, bufA, tid);
  __syncthreads();
  if (tid < 256) lds_sq_p(bufA, bufB, tid);  // F^128 in bufB
  __syncthreads();

  float* base = out + oslot(g, b, 0);
  const int c0 = w * 32;

  {
    float s = 0.f;
    float z0 = base[(size_t)c0 * 64 + lane];
    float z1 = base[(size_t)(c0 + 1) * 64 + lane];
#pragma unroll 1
    for (int i = 0; i < 32; ++i) {
      const int cn = (i + 2 < 32) ? c0 + i + 2 : c0 + 31;
      float zpf = base[(size_t)cn * 64 + lane];
      s = a_step(fr2, s, z0);
      z0 = z1;
      z1 = zpf;
    }
    carr[w][lane] = s;
  }
  __syncthreads();
  if (w == 0) {
    const float* arow = bufB + lane * ROWP;  // row `lane` of F^128
    float G = s0[(g * B_ + b) * SD + lane];
#pragma unroll 1
    for (int m = 0; m < 16; ++m) {
      gbuf[m][lane] = G;
      v2 a0 = {carr[m][lane], 0.f}, a1 = {0.f, 0.f}, a2 = {0.f, 0.f}, a3 = {0.f, 0.f};
#pragma unroll
      for (int k2 = 0; k2 < 32; ++k2) {
        v2 mr = ((const v2*)arow)[k2];
        v2 mm;
        mm.x = rl(G, 2 * k2);
        mm.y = rl(G, 2 * k2 + 1);
        if ((k2 & 3) == 0)      pkfma_s(a0, mm, mr);
        else if ((k2 & 3) == 1) pkfma_s(a1, mm, mr);
        else if ((k2 & 3) == 2) pkfma_s(a2, mm, mr);
        else                    pkfma_s(a3, mm, mr);
      }
      v2 aa = (a0 + a1) + (a2 + a3);
      G = aa.x + aa.y;
    }
  }
  __syncthreads();
  {
    float s = gbuf[w][lane];
    float zcur = base[(size_t)c0 * 64 + lane];
    float znext = base[(size_t)(c0 + 1) * 64 + lane];
#pragma unroll 1
    for (int i = 0; i < 32; ++i) {
      const int c = c0 + i;
      asm volatile("s_waitcnt vmcnt(0)" ::: "memory");
      base[(size_t)c * 64 + lane] = s;
      const int cn = (i + 2 < 32) ? c + 2 : c0 + 31;
      float zpf = base[(size_t)cn * 64 + lane];
      s = a_step(fr2, s, zcur);
      zcur = znext;
      znext = zpf;
    }
  }
}

// ---------------------------------------------------------------------------
// kC: true chunk recurrence, F-only + D-add; obs = H@z + SV@vn fused.
// F and H/SV rows via SGPR-pair pk_fma.
// ---------------------------------------------------------------------------
__global__ __launch_bounds__(256, 2) void kC(
    const float* __restrict__ vn, const float* __restrict__ Fm,
    const float* __restrict__ Hm, const float* __restrict__ SV,
    float* __restrict__ out) {
  __shared__ __align__(16) float zb[SD * 64];  // [comp][item]
  __shared__ __align__(16) float ob[OD * 64];  // [oc][item]
  const int tid = threadIdx.x;
  const int bid = (int)blockIdx.x;
  const int c4 = bid & (NC4 - 1);
  const int half = (bid >> 9) & 1;
  const int g = bid >> 10;
  const int l0 = c4 * 4;
  const int lane = tid & 63;
  const int ww = __builtin_amdgcn_readfirstlane(tid >> 6);
  const int b = half * 64 + lane;
  const int row0 = ww * 16;
  const int item = tid & 63;
  const int kg = tid >> 6;
  const float* __restrict__ Fg = Fm + g * SD * SD;
  const float* __restrict__ Hg = Hm + g * OD * SD;
  const float* __restrict__ Vg = SV + g * OD * OD;

  v2 z2[32];
  {
    const float4* ip = (const float4*)(out + oslot(g, b, c4));  // init4(c4)
#pragma unroll
    for (int q = 0; q < 16; ++q) {
      float4 f = ip[q];
      z2[2 * q] = (v2){f.x, f.y};
      z2[2 * q + 1] = (v2){f.z, f.w};
    }
  }
  float4 d4[4];
  v2 vv2[8];
  {
    const float4* dp = (const float4*)(out + slotof(g, b, l0) + row0);  // D[l0]
#pragma unroll
    for (int q = 0; q < 4; ++q) d4[q] = dp[q];
    const v2* vp = (const v2*)(vn + (((size_t)l0 * G_ + g) * B_ + b) * OD);
#pragma unroll
    for (int q = 0; q < 8; ++q) vv2[q] = vp[q];
  }

#pragma unroll 1
  for (int j = 0; j < 4; ++j) {
    const int l = l0 + j;
#pragma unroll
    for (int c = 0; c < 16; ++c) {
      const int row = row0 + c;
      const v2* fr = (const v2*)(Fg + row * SD);  // uniform -> SGPR pairs
      v2 a0 = {0.f, 0.f}, a1 = {0.f, 0.f}, a2 = {0.f, 0.f}, a3 = {0.f, 0.f};
#pragma unroll
      for (int q = 0; q < 8; ++q) {
        pkfma_s(a0, fr[4 * q + 0], z2[4 * q + 0]);
        pkfma_s(a1, fr[4 * q + 1], z2[4 * q + 1]);
        pkfma_s(a2, fr[4 * q + 2], z2[4 * q + 2]);
        pkfma_s(a3, fr[4 * q + 3], z2[4 * q + 3]);
      }
      v2 aa = (a0 + a1) + (a2 + a3);
      float dv = ((c & 3) == 0) ? d4[c >> 2].x
               : ((c & 3) == 1) ? d4[c >> 2].y
               : ((c & 3) == 2) ? d4[c >> 2].z : d4[c >> 2].w;
      zb[row * 64 + lane] = aa.x + aa.y + dv;
    }
    float4 d4n[4];
    v2 vvn[8];
    if (j != 3) {
      const float4* dp = (const float4*)(out + slotof(g, b, l + 1) + row0);
#pragma unroll
      for (int q = 0; q < 4; ++q) d4n[q] = dp[q];
      const v2* vp = (const v2*)(vn + (((size_t)(l + 1) * G_ + g) * B_ + b) * OD);
#pragma unroll
      for (int q = 0; q < 8; ++q) vvn[q] = vp[q];
    }
    lds_barrier();  // B: zb = state(l) complete
    {
      float* dst = out + slotof(g, half * 64 + item, l);
#pragma unroll
      for (int r = 0; r < 4; ++r) {
        float4 v;
        v.x = zb[(kg * 16 + 4 * r + 0) * 64 + item];
        v.y = zb[(kg * 16 + 4 * r + 1) * 64 + item];
        v.z = zb[(kg * 16 + 4 * r + 2) * 64 + item];
        v.w = zb[(kg * 16 + 4 * r + 3) * 64 + item];
        ((float4*)dst)[kg * 4 + r] = v;
      }
    }
#pragma unroll
    for (int k = 0; k < 32; ++k)
      z2[k] = (v2){zb[(2 * k) * 64 + lane], zb[(2 * k + 1) * 64 + lane]};
#pragma unroll
    for (int oc = 0; oc < 4; ++oc) {
      const int orow = ww * 4 + oc;
      const v2* hr = (const v2*)(Hg + orow * SD);  // uniform -> SGPR pairs
      const v2* vr = (const v2*)(Vg + orow * OD);  // uniform -> SGPR pairs
      v2 a0 = {0.f, 0.f}, a1 = {0.f, 0.f};
#pragma unroll
      for (int q = 0; q < 16; ++q) {
        pkfma_s(a0, hr[2 * q + 0], z2[2 * q + 0]);
        pkfma_s(a1, hr[2 * q + 1], z2[2 * q + 1]);
      }
#pragma unroll
      for (int q = 0; q < 4; ++q) {
        pkfma_s(a0, vr[2 * q + 0], vv2[2 * q + 0]);
        pkfma_s(a1, vr[2 * q + 1], vv2[2 * q + 1]);
      }
      v2 aa = a0 + a1;
      ob[orow * 64 + lane] = aa.x + aa.y;
    }
    lds_barrier();  // C: ob complete (orders zb reads before next write)
    {
      float4 v;
      v.x = ob[(4 * kg + 0) * 64 + item];
      v.y = ob[(4 * kg + 1) * 64 + item];
      v.z = ob[(4 * kg + 2) * 64 + item];
      v.w = ob[(4 * kg + 3) * 64 + item];
      float* od = out + OBS_BASE +
                  (((size_t)g * B_ + (half * 64 + item)) * L_ + l) * OD;
      ((float4*)od)[kg] = v;
    }
    if (j != 3) {
#pragma unroll
      for (int q = 0; q < 4; ++q) d4[q] = d4n[q];
#pragma unroll
      for (int q = 0; q < 8; ++q) vv2[q] = vvn[q];
    }
  }
}

extern "C" void kernel_launch(void* const* d_in, const int* in_sizes, int n_in,
                              void* d_out, int out_size, void* d_ws, size_t ws_size,
                              hipStream_t stream) {
  (void)in_sizes; (void)n_in; (void)out_size; (void)d_ws; (void)ws_size;
  const float* state0 = (const float*)d_in[0];
  const float* inputs = (const float*)d_in[1];
  const float* Fm     = (const float*)d_in[2];
  const float* Bm     = (const float*)d_in[3];
  const float* Hm     = (const float*)d_in[4];
  const float* SW     = (const float*)d_in[5];
  const float* SV     = (const float*)d_in[6];
  const float* wn     = (const float*)d_in[7];
  const float* vn     = (const float*)d_in[8];
  float* out = (float*)d_out;

  kPre<<<8192, 256, 0, stream>>>(wn, inputs, SW, Bm, out);
  kA<<<2048, 256, 0, stream>>>(Fm, out);
  kBscan2<<<256, 1024, 0, stream>>>(Fm, state0, out);
  kC<<<2048, 256, 0, stream>>>(vn, Fm, Hm, SV, out);
}

// Round 8
// 669.610 us; speedup vs baseline: 1.0119x; 1.0119x over previous
//
#include <hip/hip_runtime.h>

// Linear SSM group scan, R8.
// G=2, B=128, L=2048, SD=64, ID=16, OD=16. All fp32, exact decomposition.
//
// R8 changes (R7 post-mortem: "s"-constrained asm pk_fma destroyed the
// compiler's batched s_load_dwordx16 pipeline -> SGPR 112->64, kC +24us):
//  - kA/kC math via __builtin_elementwise_fma on v2: compiler may emit
//    v_pk_fma_f32 with the SGPR-pair matrix operand folded, while KEEPING
//    its own s_load batching/scheduling (no asm operand constraints).
//  - zb/ob LDS buffers pair-interleaved ([comp/2][item] of v2): regather is
//    32 ds_read_b64 instead of 64 ds_read_b32; cooperative stores halve
//    their LDS reads. 2-way bank aliasing = free.
// Pipeline: kPre (coloring GEMM) -> kA (zero-init chunk recurrence) ->
//           kBscan2 (3-phase block-local scan) -> kC (true recurrence+obs).
#define G_ 2
#define B_ 128
#define L_ 2048
#define SD 64
#define ID 16
#define OD 16
#define NC4 512
#define ROWP 68  // padded LDS row stride (dwords) for 64x64 matrices
#define OBS_BASE ((size_t)(G_) * B_ * L_ * SD)

typedef float v2 __attribute__((ext_vector_type(2)));

static __device__ __forceinline__ size_t slotof(int g, int b, int l) {
  return (((size_t)g * B_ + b) * L_ + l) * (size_t)SD;
}
// obs-region scratch slot: 64 floats per (g,b,c4) == obs[g,b,l0..l0+3,:]
static __device__ __forceinline__ size_t oslot(int g, int b, int c4) {
  return OBS_BASE + (((size_t)g * B_ + b) * L_ + (size_t)c4 * 4) * OD;
}
static __device__ __forceinline__ float rl(float v, int lane) {
  return __builtin_bit_cast(float, __builtin_amdgcn_readlane(__builtin_bit_cast(int, v), lane));
}
// acc += m*z elementwise; compiler free to emit v_pk_fma_f32 or 2x v_fma.
static __device__ __forceinline__ void efma(v2& acc, v2 m, v2 z) {
  acc = __builtin_elementwise_fma(m, z, acc);
}
// acc += m * z, packed fp32; m wave-uniform (SGPR pair). (kBscan2 only.)
static __device__ __forceinline__ void pkfma_s(v2& acc, v2 m, v2 z) {
  asm("v_pk_fma_f32 %0, %1, %2, %0" : "+v"(acc) : "s"(m), "v"(z));
}
// acc += a * broadcast(w.lo / w.hi)   (all VGPR, kPre)
static __device__ __forceinline__ void pkfma_blo(v2& acc, v2 a, v2 w) {
  asm("v_pk_fma_f32 %0, %1, %2, %0 op_sel:[0,0,0] op_sel_hi:[1,0,1]"
      : "+v"(acc) : "v"(a), "v"(w));
}
static __device__ __forceinline__ void pkfma_bhi(v2& acc, v2 a, v2 w) {
  asm("v_pk_fma_f32 %0, %1, %2, %0 op_sel:[0,1,0] op_sel_hi:[1,1,1]"
      : "+v"(acc) : "v"(a), "v"(w));
}
// LDS-only barrier: order ds ops without draining vmcnt.
static __device__ __forceinline__ void lds_barrier() {
  asm volatile("s_waitcnt lgkmcnt(0)\n\ts_barrier" ::: "memory");
}

// s' = A*s + add, lane = component. A rows (row=lane) in fr2 (32 v2 regs).
static __device__ __forceinline__ float a_step(const v2 (&fr2)[32], float s, float add) {
  v2 a0 = {add, 0.f}, a1 = {0.f, 0.f}, a2 = {0.f, 0.f}, a3 = {0.f, 0.f};
#pragma unroll
  for (int k2 = 0; k2 < 32; ++k2) {
    v2 m;
    m.x = rl(s, 2 * k2);
    m.y = rl(s, 2 * k2 + 1);
    if ((k2 & 3) == 0)      pkfma_s(a0, m, fr2[k2]);
    else if ((k2 & 3) == 1) pkfma_s(a1, m, fr2[k2]);
    else if ((k2 & 3) == 2) pkfma_s(a2, m, fr2[k2]);
    else                    pkfma_s(a3, m, fr2[k2]);
  }
  v2 aa = (a0 + a1) + (a2 + a3);
  return aa.x + aa.y;
}

// C = A*A (64x64, ROWP-padded LDS), 256 threads. Caller syncs before/after.
static __device__ void lds_sq_p(const float* A, float* C, int tid) {
  const int r = tid & 63, q = tid >> 6;
  const float4* Ar = (const float4*)(A + r * ROWP);
  float acc[16];
#pragma unroll
  for (int c = 0; c < 16; ++c) acc[c] = 0.f;
#pragma unroll 1
  for (int k4 = 0; k4 < 16; ++k4) {
    float4 af = Ar[k4];
#pragma unroll
    for (int kk = 0; kk < 4; ++kk) {
      float a = (kk == 0) ? af.x : (kk == 1) ? af.y : (kk == 2) ? af.z : af.w;
      const float4* Bk = (const float4*)(A + (k4 * 4 + kk) * ROWP + q * 16);
#pragma unroll
      for (int c = 0; c < 4; ++c) {
        float4 bv = Bk[c];
        acc[4 * c + 0] = fmaf(a, bv.x, acc[4 * c + 0]);
        acc[4 * c + 1] = fmaf(a, bv.y, acc[4 * c + 1]);
        acc[4 * c + 2] = fmaf(a, bv.z, acc[4 * c + 2]);
        acc[4 * c + 3] = fmaf(a, bv.w, acc[4 * c + 3]);
      }
    }
  }
  float4* Cr = (float4*)(C + r * ROWP + q * 16);
#pragma unroll
  for (int c = 0; c < 4; ++c)
    Cr[c] = make_float4(acc[4 * c], acc[4 * c + 1], acc[4 * c + 2], acc[4 * c + 3]);
}

// ---------------------------------------------------------------------------
// kPre: D = SW@wn + B@u for one (g, l, b-half) per block -> state slots.
// ---------------------------------------------------------------------------
__global__ __launch_bounds__(256) void kPre(
    const float* __restrict__ wn, const float* __restrict__ inp,
    const float* __restrict__ SW, const float* __restrict__ Bm,
    float* __restrict__ out) {
  __shared__ __align__(16) float Mt[80 * 64];  // k<64: SW^T, k>=64: B^T
  __shared__ __align__(16) float Nt[80 * 64];  // k<64: wn^T, k>=64: u^T
  const int tid = threadIdx.x;
  const int bid = (int)blockIdx.x;
  const int g = bid >> 12;
  const int rem = bid & 4095;
  const int l = rem >> 1;
  const int b0 = (rem & 1) * 64;
  {
    const int row = tid >> 2;
    const int k0 = (tid & 3) * 16;
    const float4* sp = (const float4*)(SW + (g * SD + row) * SD + k0);
#pragma unroll
    for (int q = 0; q < 4; ++q) {
      float4 v = sp[q];
      Mt[(k0 + 4 * q + 0) * 64 + row] = v.x;
      Mt[(k0 + 4 * q + 1) * 64 + row] = v.y;
      Mt[(k0 + 4 * q + 2) * 64 + row] = v.z;
      Mt[(k0 + 4 * q + 3) * 64 + row] = v.w;
    }
    const int k2 = (tid & 3) * 4;
    float4 bv = *(const float4*)(Bm + (g * SD + row) * ID + k2);
    Mt[(64 + k2 + 0) * 64 + row] = bv.x;
    Mt[(64 + k2 + 1) * 64 + row] = bv.y;
    Mt[(64 + k2 + 2) * 64 + row] = bv.z;
    Mt[(64 + k2 + 3) * 64 + row] = bv.w;
  }
  {
    const int item = tid & 63;
    const int kq = tid >> 6;
    const float4* wp =
        (const float4*)(wn + (((size_t)l * G_ + g) * B_ + b0 + item) * SD + kq * 16);
#pragma unroll
    for (int q = 0; q < 4; ++q) {
      float4 v = wp[q];
      const int k = kq * 16 + 4 * q;
      Nt[(k + 0) * 64 + item] = v.x;
      Nt[(k + 1) * 64 + item] = v.y;
      Nt[(k + 2) * 64 + item] = v.z;
      Nt[(k + 3) * 64 + item] = v.w;
    }
    const int item2 = tid >> 2;
    const int k2 = (tid & 3) * 4;
    float4 uv = *(const float4*)(inp + (((size_t)g * B_ + b0 + item2) * L_ + l) * ID + k2);
    Nt[(64 + k2 + 0) * 64 + item2] = uv.x;
    Nt[(64 + k2 + 1) * 64 + item2] = uv.y;
    Nt[(64 + k2 + 2) * 64 + item2] = uv.z;
    Nt[(64 + k2 + 3) * 64 + item2] = uv.w;
  }
  __syncthreads();
  const int i0 = (tid & 15) * 4;
  const int r0 = (tid >> 4) * 4;
  v2 acc2[2][4];
#pragma unroll
  for (int r = 0; r < 2; ++r)
#pragma unroll
    for (int i = 0; i < 4; ++i) acc2[r][i] = (v2){0.f, 0.f};
#pragma unroll 4
  for (int k = 0; k < 80; ++k) {
    const v2* ap = (const v2*)(Mt + k * 64 + r0);
    const v2* wp = (const v2*)(Nt + k * 64 + i0);
    v2 a20 = ap[0], a21 = ap[1];
    v2 w20 = wp[0], w21 = wp[1];
#pragma unroll
    for (int r = 0; r < 2; ++r) {
      v2 ar = (r == 0) ? a20 : a21;
      pkfma_blo(acc2[r][0], ar, w20);
      pkfma_bhi(acc2[r][1], ar, w20);
      pkfma_blo(acc2[r][2], ar, w21);
      pkfma_bhi(acc2[r][3], ar, w21);
    }
  }
#pragma unroll
  for (int i = 0; i < 4; ++i) {
    float4 v = make_float4(acc2[0][i].x, acc2[0][i].y, acc2[1][i].x, acc2[1][i].y);
    *(float4*)(out + slotof(g, b0 + i0 + i, l) + r0) = v;
  }
}

// ---------------------------------------------------------------------------
// kA: zero-init chunk recurrence, F-only. z(l0) = D[l0]; 3 F-steps; writes
// zend4(c4) to obs scratch. zb pair-interleaved: zb2[p][item] = comps 2p,2p+1.
// ---------------------------------------------------------------------------
__global__ __launch_bounds__(256, 2) void kA(const float* __restrict__ Fm,
                                             float* __restrict__ out) {
  __shared__ __align__(16) v2 zb2[32 * 64];  // 16 KB, [comp-pair][item]
  const int tid = threadIdx.x;
  const int bid = (int)blockIdx.x;
  const int c4 = bid & (NC4 - 1);
  const int half = (bid >> 9) & 1;
  const int g = bid >> 10;
  const int l0 = c4 * 4;
  const int lane = tid & 63;
  const int ww = __builtin_amdgcn_readfirstlane(tid >> 6);
  const int b = half * 64 + lane;
  const int row0 = ww * 16;
  const float* __restrict__ Fg = Fm + g * SD * SD;
  float* zbf = (float*)zb2;

  v2 z2[32];
  {
    const float4* ip = (const float4*)(out + slotof(g, b, l0));  // D[l0]
#pragma unroll
    for (int q = 0; q < 16; ++q) {
      float4 f = ip[q];
      z2[2 * q] = (v2){f.x, f.y};
      z2[2 * q + 1] = (v2){f.z, f.w};
    }
  }
  float4 d4[4];
  {
    const float4* dp = (const float4*)(out + slotof(g, b, l0 + 1) + row0);
#pragma unroll
    for (int q = 0; q < 4; ++q) d4[q] = dp[q];
  }

#pragma unroll 1
  for (int j = 1; j < 4; ++j) {
    if (j != 1) lds_barrier();  // prev regather drained
#pragma unroll
    for (int c = 0; c < 16; ++c) {
      const int row = row0 + c;
      const v2* fr = (const v2*)(Fg + row * SD);  // uniform -> s_load stream
      v2 a0 = {0.f, 0.f}, a1 = {0.f, 0.f}, a2 = {0.f, 0.f}, a3 = {0.f, 0.f};
#pragma unroll
      for (int q = 0; q < 8; ++q) {
        efma(a0, fr[4 * q + 0], z2[4 * q + 0]);
        efma(a1, fr[4 * q + 1], z2[4 * q + 1]);
        efma(a2, fr[4 * q + 2], z2[4 * q + 2]);
        efma(a3, fr[4 * q + 3], z2[4 * q + 3]);
      }
      v2 aa = (a0 + a1) + (a2 + a3);
      float dv = ((c & 3) == 0) ? d4[c >> 2].x
               : ((c & 3) == 1) ? d4[c >> 2].y
               : ((c & 3) == 2) ? d4[c >> 2].z : d4[c >> 2].w;
      zbf[(row >> 1) * 128 + lane * 2 + (row & 1)] = aa.x + aa.y + dv;
    }
    float4 d4n[4];
    if (j != 3) {  // prefetch D[l0+j+1]; in flight across barrier + regather
      const float4* dp = (const float4*)(out + slotof(g, b, l0 + j + 1) + row0);
#pragma unroll
      for (int q = 0; q < 4; ++q) d4n[q] = dp[q];
    }
    lds_barrier();  // zb complete
    if (j != 3) {
#pragma unroll
      for (int k = 0; k < 32; ++k) z2[k] = zb2[k * 64 + lane];  // ds_read_b64
#pragma unroll
      for (int q = 0; q < 4; ++q) d4[q] = d4n[q];
    }
  }
  // cooperative zend4 store -> obs scratch slot(c4)
  {
    const int item = tid & 63;
    const int kg = tid >> 6;
    float* dst = out + oslot(g, half * 64 + item, c4);
#pragma unroll
    for (int r = 0; r < 4; ++r) {
      v2 p0 = zb2[(kg * 8 + 2 * r + 0) * 64 + item];
      v2 p1 = zb2[(kg * 8 + 2 * r + 1) * 64 + item];
      ((float4*)dst)[kg * 4 + r] = make_float4(p0.x, p0.y, p1.x, p1.y);
    }
  }
}

// ---------------------------------------------------------------------------
// kBscan2: 3-phase init4 scan. Block = (g,b), 1024 threads, 16 waves.
// ---------------------------------------------------------------------------
__global__ __launch_bounds__(1024, 4) void kBscan2(const float* __restrict__ Fm,
                                                   const float* __restrict__ s0,
                                                   float* __restrict__ out) {
  __shared__ __align__(16) float bufA[SD * ROWP];
  __shared__ __align__(16) float bufB[SD * ROWP];
  __shared__ float carr[16][64];
  __shared__ float gbuf[16][64];
  const int tid = threadIdx.x;
  const int bid = (int)blockIdx.x;
  const int g = bid >> 7;
  const int b = bid & 127;
  const int lane = tid & 63;
  const int w = __builtin_amdgcn_readfirstlane(tid >> 6);

  {
    const float* Fg = Fm + g * SD * SD;
    for (int i = tid; i < SD * SD; i += 1024)
      bufA[(i >> 6) * ROWP + (i & 63)] = Fg[i];
  }
  __syncthreads();
  if (tid < 256) lds_sq_p(bufA, bufB, tid);
  __syncthreads();
  if (tid < 256) lds_sq_p(bufB, bufA, tid);
  __syncthreads();
  v2 fr2[32];  // row `lane` of F^4
  {
    const v2* rp = (const v2*)(bufA + lane * ROWP);
#pragma unroll
    for (int k = 0; k < 32; ++k) fr2[k] = rp[k];
  }
  __syncthreads();
  if (tid < 256) lds_sq_p(bufA, bufB, tid);
  __syncthreads();
  if (tid < 256) lds_sq_p(bufB, bufA, tid);
  __syncthreads();
  if (tid < 256) lds_sq_p(bufA, bufB, tid);
  __syncthreads();
  if (tid < 256) lds_sq_p(bufB, bufA, tid);
  __syncthreads();
  if (tid < 256) lds_sq_p(bufA, bufB, tid);  // F^128 in bufB
  __syncthreads();

  float* base = out + oslot(g, b, 0);
  const int c0 = w * 32;

  {
    float s = 0.f;
    float z0 = base[(size_t)c0 * 64 + lane];
    float z1 = base[(size_t)(c0 + 1) * 64 + lane];
#pragma unroll 1
    for (int i = 0; i < 32; ++i) {
      const int cn = (i + 2 < 32) ? c0 + i + 2 : c0 + 31;
      float zpf = base[(size_t)cn * 64 + lane];
      s = a_step(fr2, s, z0);
      z0 = z1;
      z1 = zpf;
    }
    carr[w][lane] = s;
  }
  __syncthreads();
  if (w == 0) {
    const float* arow = bufB + lane * ROWP;  // row `lane` of F^128
    float G = s0[(g * B_ + b) * SD + lane];
#pragma unroll 1
    for (int m = 0; m < 16; ++m) {
      gbuf[m][lane] = G;
      v2 a0 = {carr[m][lane], 0.f}, a1 = {0.f, 0.f}, a2 = {0.f, 0.f}, a3 = {0.f, 0.f};
#pragma unroll
      for (int k2 = 0; k2 < 32; ++k2) {
        v2 mr = ((const v2*)arow)[k2];
        v2 mm;
        mm.x = rl(G, 2 * k2);
        mm.y = rl(G, 2 * k2 + 1);
        if ((k2 & 3) == 0)      pkfma_s(a0, mm, mr);
        else if ((k2 & 3) == 1) pkfma_s(a1, mm, mr);
        else if ((k2 & 3) == 2) pkfma_s(a2, mm, mr);
        else                    pkfma_s(a3, mm, mr);
      }
      v2 aa = (a0 + a1) + (a2 + a3);
      G = aa.x + aa.y;
    }
  }
  __syncthreads();
  {
    float s = gbuf[w][lane];
    float zcur = base[(size_t)c0 * 64 + lane];
    float znext = base[(size_t)(c0 + 1) * 64 + lane];
#pragma unroll 1
    for (int i = 0; i < 32; ++i) {
      const int c = c0 + i;
      asm volatile("s_waitcnt vmcnt(0)" ::: "memory");
      base[(size_t)c * 64 + lane] = s;
      const int cn = (i + 2 < 32) ? c + 2 : c0 + 31;
      float zpf = base[(size_t)cn * 64 + lane];
      s = a_step(fr2, s, zcur);
      zcur = znext;
      znext = zpf;
    }
  }
}

// ---------------------------------------------------------------------------
// kC: true chunk recurrence, F-only + D-add; obs = H@z + SV@vn fused.
// zb/ob pair-interleaved.
// ---------------------------------------------------------------------------
__global__ __launch_bounds__(256, 2) void kC(
    const float* __restrict__ vn, const float* __restrict__ Fm,
    const float* __restrict__ Hm, const float* __restrict__ SV,
    float* __restrict__ out) {
  __shared__ __align__(16) v2 zb2[32 * 64];  // 16 KB [comp-pair][item]
  __shared__ __align__(16) v2 ob2[8 * 64];   // 4 KB  [oc-pair][item]
  const int tid = threadIdx.x;
  const int bid = (int)blockIdx.x;
  const int c4 = bid & (NC4 - 1);
  const int half = (bid >> 9) & 1;
  const int g = bid >> 10;
  const int l0 = c4 * 4;
  const int lane = tid & 63;
  const int ww = __builtin_amdgcn_readfirstlane(tid >> 6);
  const int b = half * 64 + lane;
  const int row0 = ww * 16;
  const int item = tid & 63;
  const int kg = tid >> 6;
  const float* __restrict__ Fg = Fm + g * SD * SD;
  const float* __restrict__ Hg = Hm + g * OD * SD;
  const float* __restrict__ Vg = SV + g * OD * OD;
  float* zbf = (float*)zb2;
  float* obf = (float*)ob2;

  v2 z2[32];
  {
    const float4* ip = (const float4*)(out + oslot(g, b, c4));  // init4(c4)
#pragma unroll
    for (int q = 0; q < 16; ++q) {
      float4 f = ip[q];
      z2[2 * q] = (v2){f.x, f.y};
      z2[2 * q + 1] = (v2){f.z, f.w};
    }
  }
  float4 d4[4];
  v2 vv2[8];
  {
    const float4* dp = (const float4*)(out + slotof(g, b, l0) + row0);  // D[l0]
#pragma unroll
    for (int q = 0; q < 4; ++q) d4[q] = dp[q];
    const v2* vp = (const v2*)(vn + (((size_t)l0 * G_ + g) * B_ + b) * OD);
#pragma unroll
    for (int q = 0; q < 8; ++q) vv2[q] = vp[q];
  }

#pragma unroll 1
  for (int j = 0; j < 4; ++j) {
    const int l = l0 + j;
#pragma unroll
    for (int c = 0; c < 16; ++c) {
      const int row = row0 + c;
      const v2* fr = (const v2*)(Fg + row * SD);  // uniform -> s_load stream
      v2 a0 = {0.f, 0.f}, a1 = {0.f, 0.f}, a2 = {0.f, 0.f}, a3 = {0.f, 0.f};
#pragma unroll
      for (int q = 0; q < 8; ++q) {
        efma(a0, fr[4 * q + 0], z2[4 * q + 0]);
        efma(a1, fr[4 * q + 1], z2[4 * q + 1]);
        efma(a2, fr[4 * q + 2], z2[4 * q + 2]);
        efma(a3, fr[4 * q + 3], z2[4 * q + 3]);
      }
      v2 aa = (a0 + a1) + (a2 + a3);
      float dv = ((c & 3) == 0) ? d4[c >> 2].x
               : ((c & 3) == 1) ? d4[c >> 2].y
               : ((c & 3) == 2) ? d4[c >> 2].z : d4[c >> 2].w;
      zbf[(row >> 1) * 128 + lane * 2 + (row & 1)] = aa.x + aa.y + dv;
    }
    float4 d4n[4];
    v2 vvn[8];
    if (j != 3) {
      const float4* dp = (const float4*)(out + slotof(g, b, l + 1) + row0);
#pragma unroll
      for (int q = 0; q < 4; ++q) d4n[q] = dp[q];
      const v2* vp = (const v2*)(vn + (((size_t)(l + 1) * G_ + g) * B_ + b) * OD);
#pragma unroll
      for (int q = 0; q < 8; ++q) vvn[q] = vp[q];
    }
    lds_barrier();  // B: zb = state(l) complete
    {
      float* dst = out + slotof(g, half * 64 + item, l);
#pragma unroll
      for (int r = 0; r < 4; ++r) {
        v2 p0 = zb2[(kg * 8 + 2 * r + 0) * 64 + item];
        v2 p1 = zb2[(kg * 8 + 2 * r + 1) * 64 + item];
        ((float4*)dst)[kg * 4 + r] = make_float4(p0.x, p0.y, p1.x, p1.y);
      }
    }
#pragma unroll
    for (int k = 0; k < 32; ++k) z2[k] = zb2[k * 64 + lane];  // ds_read_b64
#pragma unroll
    for (int oc = 0; oc < 4; ++oc) {
      const int orow = ww * 4 + oc;
      const v2* hr = (const v2*)(Hg + orow * SD);
      const v2* vr = (const v2*)(Vg + orow * OD);
      v2 a0 = {0.f, 0.f}, a1 = {0.f, 0.f};
#pragma unroll
      for (int q = 0; q < 16; ++q) {
        efma(a0, hr[2 * q + 0], z2[2 * q + 0]);
        efma(a1, hr[2 * q + 1], z2[2 * q + 1]);
      }
#pragma unroll
      for (int q = 0; q < 4; ++q) {
        efma(a0, vr[2 * q + 0], vv2[2 * q + 0]);
        efma(a1, vr[2 * q + 1], vv2[2 * q + 1]);
      }
      v2 aa = a0 + a1;
      obf[(orow >> 1) * 128 + lane * 2 + (orow & 1)] = aa.x + aa.y;
    }
    lds_barrier();  // C: ob complete (orders zb reads before next write)
    {
      v2 p0 = ob2[(2 * kg + 0) * 64 + item];
      v2 p1 = ob2[(2 * kg + 1) * 64 + item];
      float* od = out + OBS_BASE +
                  (((size_t)g * B_ + (half * 64 + item)) * L_ + l) * OD;
      ((float4*)od)[kg] = make_float4(p0.x, p0.y, p1.x, p1.y);
    }
    if (j != 3) {
#pragma unroll
      for (int q = 0; q < 4; ++q) d4[q] = d4n[q];
#pragma unroll
      for (int q = 0; q < 8; ++q) vv2[q] = vvn[q];
    }
  }
}

extern "C" void kernel_launch(void* const* d_in, const int* in_sizes, int n_in,
                              void* d_out, int out_size, void* d_ws, size_t ws_size,
                              hipStream_t stream) {
  (void)in_sizes; (void)n_in; (void)out_size; (void)d_ws; (void)ws_size;
  const float* state0 = (const float*)d_in[0];
  const float* inputs = (const float*)d_in[1];
  const float* Fm     = (const float*)d_in[2];
  const float* Bm     = (const float*)d_in[3];
  const float* Hm     = (const float*)d_in[4];
  const float* SW     = (const float*)d_in[5];
  const float* SV     = (const float*)d_in[6];
  const float* wn     = (const float*)d_in[7];
  const float* vn     = (const float*)d_in[8];
  float* out = (float*)d_out;

  kPre<<<8192, 256, 0, stream>>>(wn, inputs, SW, Bm, out);
  kA<<<2048, 256, 0, stream>>>(Fm, out);
  kBscan2<<<256, 1024, 0, stream>>>(Fm, state0, out);
  kC<<<2048, 256, 0, stream>>>(vn, Fm, Hm, SV, out);
}